// Round 1
// baseline (109882.910 us; speedup 1.0000x reference)
//
#include <hip/hip_runtime.h>
#include <cstdint>
#include <cstddef>

#define SEQ   2048
#define BATCH 64
#define HID   512
#define NSLICE 8
#define NGROUP 32

// ---------------------------------------------------------------------------
// proj GEMM: C[m][n] = sum_k A[m][k] * W[n][k] + bias[n]
// A: [M][512] row-major, W: [512][512] row-major (NT layout -> both row reads)
// BM=128 BN=128 BK=16, 256 threads, per-thread 8 rows x (4+4) cols
// ---------------------------------------------------------------------------
__global__ __launch_bounds__(256)
void proj_gemm(const float* __restrict__ A, const float* __restrict__ W,
               const float* __restrict__ bias, float* __restrict__ C)
{
    __shared__ float As[16][132];   // transposed: As[k][row], pad 132
    __shared__ float Bs[16][132];   // Bs[k][col]
    const int t  = threadIdx.x;
    const int bm = blockIdx.x >> 2;     // 1024 m-tiles
    const int bn = blockIdx.x & 3;      // 4 n-tiles
    const int m0 = bm * 128;
    const int n0 = bn * 128;
    const int tn = t & 15;
    const int tm = t >> 4;

    float acc[8][8];
#pragma unroll
    for (int i = 0; i < 8; ++i)
#pragma unroll
        for (int j = 0; j < 8; ++j) acc[i][j] = 0.f;

    const int lrow = t >> 2;   // 0..63
    const int lk4  = t & 3;    // float4 index within 16-wide k tile

    for (int kk = 0; kk < 512; kk += 16) {
#pragma unroll
        for (int i = 0; i < 2; ++i) {
            const int row = lrow + i * 64;
            float4 va = *(const float4*)&A[(size_t)(m0 + row) * 512 + kk + lk4 * 4];
            As[lk4 * 4 + 0][row] = va.x;
            As[lk4 * 4 + 1][row] = va.y;
            As[lk4 * 4 + 2][row] = va.z;
            As[lk4 * 4 + 3][row] = va.w;
            float4 vb = *(const float4*)&W[(size_t)(n0 + row) * 512 + kk + lk4 * 4];
            Bs[lk4 * 4 + 0][row] = vb.x;
            Bs[lk4 * 4 + 1][row] = vb.y;
            Bs[lk4 * 4 + 2][row] = vb.z;
            Bs[lk4 * 4 + 3][row] = vb.w;
        }
        __syncthreads();
#pragma unroll
        for (int k = 0; k < 16; ++k) {
            float4 a0 = *(const float4*)&As[k][tm * 8];
            float4 a1 = *(const float4*)&As[k][tm * 8 + 4];
            float4 b0 = *(const float4*)&Bs[k][tn * 4];
            float4 b1 = *(const float4*)&Bs[k][64 + tn * 4];
            float ar[8] = {a0.x, a0.y, a0.z, a0.w, a1.x, a1.y, a1.z, a1.w};
            float bc[8] = {b0.x, b0.y, b0.z, b0.w, b1.x, b1.y, b1.z, b1.w};
#pragma unroll
            for (int i = 0; i < 8; ++i)
#pragma unroll
                for (int j = 0; j < 8; ++j)
                    acc[i][j] = fmaf(ar[i], bc[j], acc[i][j]);
        }
        __syncthreads();
    }

    float4 bv0 = *(const float4*)&bias[n0 + tn * 4];
    float4 bv1 = *(const float4*)&bias[n0 + 64 + tn * 4];
    const float bb[8] = {bv0.x, bv0.y, bv0.z, bv0.w, bv1.x, bv1.y, bv1.z, bv1.w};
#pragma unroll
    for (int i = 0; i < 8; ++i) {
        const size_t rowoff = (size_t)(m0 + tm * 8 + i) * 512 + n0;
        float4 o0, o1;
        o0.x = acc[i][0] + bb[0]; o0.y = acc[i][1] + bb[1];
        o0.z = acc[i][2] + bb[2]; o0.w = acc[i][3] + bb[3];
        o1.x = acc[i][4] + bb[4]; o1.y = acc[i][5] + bb[5];
        o1.z = acc[i][6] + bb[6]; o1.w = acc[i][7] + bb[7];
        *(float4*)&C[rowoff + tn * 4] = o0;
        *(float4*)&C[rowoff + 64 + tn * 4] = o1;
    }
}

// ---------------------------------------------------------------------------
// Recurrent scan, one layer. Persistent cooperative kernel, grid = 256 WGs.
// Group g (32 groups) handles batch pair (2g, 2g+1) with 8 slice-WGs; slice s
// owns rows [64s, 64s+64) of W_hh resident in LDS (f32, 128 KB, swizzled).
// Per step: stage h (both batch elems) from global -> LDS, compute 64x512
// matvec x2, tanh, write h slice + output, then flag-sync the 8 WGs.
// h state is parity double-buffered in global: step reads slot (step&1),
// writes slot ((step+1)&1). blockIdx = s*32 + g keeps a group on one XCD.
// ---------------------------------------------------------------------------
__global__ __launch_bounds__(256)
void rnn_scan(const float* __restrict__ proj, const float* __restrict__ Whh,
              const float* __restrict__ bhh, float* __restrict__ out,
              float* __restrict__ hidden, float* __restrict__ hbuf,
              unsigned int* __restrict__ flags)
{
    extern __shared__ float lds[];
    float4* Wv  = (float4*)lds;                    // 8192 float4 = 128 KB
    float4* hS  = (float4*)(lds + 32768);          // 2 x 144 float4 (padded)
    float*  part = lds + 32768 + 1152;             // [16][2][64] = 8 KB
    float*  bsl  = lds + 32768 + 1152 + 2048;      // [64]

    const int t    = threadIdx.x;
    const int g    = blockIdx.x & 31;
    const int s    = blockIdx.x >> 5;
    const int b0   = g * 2;
    const int base = s * 64;

    // Load W_hh slice into LDS, float4 layout Wv[k4][r] with XOR swizzle on
    // low 4 row bits so both the load and the (rq,kq) compute reads are
    // conflict-free.
#pragma unroll 4
    for (int i = 0; i < 32; ++i) {
        const int idx = i * 256 + t;        // 0..8191
        const int r   = idx >> 7;           // 0..63
        const int k4  = idx & 127;          // float4 along k
        float4 v = *(const float4*)&Whh[(size_t)(base + r) * 512 + k4 * 4];
        Wv[k4 * 64 + ((r & 48) | ((r ^ k4) & 15))] = v;
    }
    if (t < 64) bsl[t] = bhh[base + t];

    const int rq = t & 15;   // rows rq, rq+16, rq+32, rq+48
    const int kq = t >> 4;   // k range [kq*32, kq*32+32)
    __syncthreads();

    for (int step = 0; step < SEQ; ++step) {
        // ---- stage h (both batch elems, 1024 floats) into padded LDS ----
        {
            const float* hsrc = hbuf + (size_t)(step & 1) * BATCH * HID + (size_t)b0 * HID;
            const int c = t & 127;
            const int b = t >> 7;
            float4 v = *(const float4*)&hsrc[b * 512 + c * 4];
            hS[b * 144 + c + (c >> 3)] = v;
        }
        __syncthreads();

        // ---- partial matvec: 4 rows x 32 k per thread, 2 batch elems ----
        float acc0[4] = {0.f, 0.f, 0.f, 0.f};
        float acc1[4] = {0.f, 0.f, 0.f, 0.f};
#pragma unroll
        for (int kb = 0; kb < 8; ++kb) {
            const int k4 = kq * 8 + kb;
            const int hp = k4 + (k4 >> 3);
            float4 ha = hS[hp];
            float4 hb = hS[144 + hp];
#pragma unroll
            for (int rr = 0; rr < 4; ++rr) {
                float4 w = Wv[k4 * 64 + rr * 16 + (rq ^ (k4 & 15))];
                acc0[rr] += w.x * ha.x + w.y * ha.y + w.z * ha.z + w.w * ha.w;
                acc1[rr] += w.x * hb.x + w.y * hb.y + w.z * hb.z + w.w * hb.w;
            }
        }
#pragma unroll
        for (int rr = 0; rr < 4; ++rr) {
            const int r = rq + rr * 16;
            part[kq * 128 + r]      = acc0[rr];
            part[kq * 128 + 64 + r] = acc1[rr];
        }
        __syncthreads();

        // ---- reduce 16 partials, add proj + bias, tanh, write ----
        if (t < 128) {
            const int b = t >> 6;
            const int r = t & 63;
            float sum = 0.f;
#pragma unroll
            for (int q = 0; q < 16; ++q) sum += part[q * 128 + b * 64 + r];
            const size_t oidx = (size_t)step * BATCH * HID + (size_t)(b0 + b) * HID + base + r;
            const float y  = proj[oidx] + bsl[r] + sum;
            const float hn = tanhf(y);
            out[oidx] = hn;
            hbuf[(size_t)((step + 1) & 1) * BATCH * HID + (size_t)(b0 + b) * HID + base + r] = hn;
            if (step == SEQ - 1) hidden[(size_t)(b0 + b) * HID + base + r] = hn;
        }
        __threadfence();
        __syncthreads();
        if (t == 0) {
            __hip_atomic_fetch_add(&flags[g], 1u, __ATOMIC_RELEASE, __HIP_MEMORY_SCOPE_AGENT);
            const unsigned target = (unsigned)(NSLICE * (step + 1));
            while (__hip_atomic_load(&flags[g], __ATOMIC_ACQUIRE, __HIP_MEMORY_SCOPE_AGENT) < target) {
                __builtin_amdgcn_s_sleep(1);
            }
        }
        __syncthreads();
    }
}

// ---------------------------------------------------------------------------
extern "C" void kernel_launch(void* const* d_in, const int* in_sizes, int n_in,
                              void* d_out, int out_size, void* d_ws, size_t ws_size,
                              hipStream_t stream)
{
    (void)in_sizes; (void)n_in; (void)out_size; (void)ws_size;

    const float* x    = (const float*)d_in[0];
    const float* Wih0 = (const float*)d_in[1];
    const float* Whh0 = (const float*)d_in[2];
    const float* bih0 = (const float*)d_in[3];
    const float* bhh0 = (const float*)d_in[4];
    const float* Wih1 = (const float*)d_in[5];
    const float* Whh1 = (const float*)d_in[6];
    const float* bih1 = (const float*)d_in[7];
    const float* bhh1 = (const float*)d_in[8];

    float* out1   = (float*)d_out;                        // [S][B][H]
    float* hidden = out1 + (size_t)SEQ * BATCH * HID;     // [2][B][H]

    float* proj   = (float*)d_ws;                         // [S][B][H] f32
    float* hbuf0  = proj + (size_t)SEQ * BATCH * HID;     // [2][B][H]
    float* hbuf1  = hbuf0 + 2 * BATCH * HID;              // [2][B][H]
    unsigned* flags0 = (unsigned*)(hbuf1 + 2 * BATCH * HID);
    unsigned* flags1 = flags0 + 32;

    // zero both h-state buffers + both flag arrays (contiguous region)
    hipMemsetAsync(hbuf0, 0, (size_t)4 * BATCH * HID * sizeof(float) + 256, stream);

    const size_t shmem = (size_t)(32768 + 1152 + 2048 + 64) * sizeof(float); // 144128 B
    (void)hipFuncSetAttribute((const void*)rnn_scan,
                              hipFuncAttributeMaxDynamicSharedMemorySize, (int)shmem);

    // ---- layer 0 ----
    proj_gemm<<<dim3(4096), dim3(256), 0, stream>>>(x, Wih0, bih0, proj);
    {
        const float* p = proj; const float* w = Whh0; const float* bb = bhh0;
        float* o = out1; float* hd = hidden; float* hb = hbuf0; unsigned* fl = flags0;
        void* args[] = {&p, &w, &bb, &o, &hd, &hb, &fl};
        hipLaunchCooperativeKernel((const void*)rnn_scan, dim3(256), dim3(256),
                                   args, (unsigned)shmem, stream);
    }

    // ---- layer 1 (out0 staged in d_out's out1 region) ----
    proj_gemm<<<dim3(4096), dim3(256), 0, stream>>>(out1, Wih1, bih1, proj);
    {
        const float* p = proj; const float* w = Whh1; const float* bb = bhh1;
        float* o = out1; float* hd = hidden + BATCH * HID; float* hb = hbuf1; unsigned* fl = flags1;
        void* args[] = {&p, &w, &bb, &o, &hd, &hb, &fl};
        hipLaunchCooperativeKernel((const void*)rnn_scan, dim3(256), dim3(256),
                                   args, (unsigned)shmem, stream);
    }
}

// Round 2
// 12775.734 us; speedup vs baseline: 8.6009x; 8.6009x over previous
//
#include <hip/hip_runtime.h>
#include <cstdint>
#include <cstddef>

#define SEQ   2048
#define BATCH 64
#define HID   512
#define NSLICE 8
#define NGROUP 32

// ---------------------------------------------------------------------------
// proj GEMM: C[m][n] = sum_k A[m][k] * W[n][k] + bias[n]
// A: [M][512] row-major, W: [512][512] row-major (NT layout -> both row reads)
// BM=128 BN=128 BK=16, 256 threads, per-thread 8 rows x (4+4) cols
// ---------------------------------------------------------------------------
__global__ __launch_bounds__(256)
void proj_gemm(const float* __restrict__ A, const float* __restrict__ W,
               const float* __restrict__ bias, float* __restrict__ C)
{
    __shared__ float As[16][132];   // transposed: As[k][row], pad 132
    __shared__ float Bs[16][132];   // Bs[k][col]
    const int t  = threadIdx.x;
    const int bm = blockIdx.x >> 2;     // 1024 m-tiles
    const int bn = blockIdx.x & 3;      // 4 n-tiles
    const int m0 = bm * 128;
    const int n0 = bn * 128;
    const int tn = t & 15;
    const int tm = t >> 4;

    float acc[8][8];
#pragma unroll
    for (int i = 0; i < 8; ++i)
#pragma unroll
        for (int j = 0; j < 8; ++j) acc[i][j] = 0.f;

    const int lrow = t >> 2;   // 0..63
    const int lk4  = t & 3;    // float4 index within 16-wide k tile

    for (int kk = 0; kk < 512; kk += 16) {
#pragma unroll
        for (int i = 0; i < 2; ++i) {
            const int row = lrow + i * 64;
            float4 va = *(const float4*)&A[(size_t)(m0 + row) * 512 + kk + lk4 * 4];
            As[lk4 * 4 + 0][row] = va.x;
            As[lk4 * 4 + 1][row] = va.y;
            As[lk4 * 4 + 2][row] = va.z;
            As[lk4 * 4 + 3][row] = va.w;
            float4 vb = *(const float4*)&W[(size_t)(n0 + row) * 512 + kk + lk4 * 4];
            Bs[lk4 * 4 + 0][row] = vb.x;
            Bs[lk4 * 4 + 1][row] = vb.y;
            Bs[lk4 * 4 + 2][row] = vb.z;
            Bs[lk4 * 4 + 3][row] = vb.w;
        }
        __syncthreads();
#pragma unroll
        for (int k = 0; k < 16; ++k) {
            float4 a0 = *(const float4*)&As[k][tm * 8];
            float4 a1 = *(const float4*)&As[k][tm * 8 + 4];
            float4 b0 = *(const float4*)&Bs[k][tn * 4];
            float4 b1 = *(const float4*)&Bs[k][64 + tn * 4];
            float ar[8] = {a0.x, a0.y, a0.z, a0.w, a1.x, a1.y, a1.z, a1.w};
            float bc[8] = {b0.x, b0.y, b0.z, b0.w, b1.x, b1.y, b1.z, b1.w};
#pragma unroll
            for (int i = 0; i < 8; ++i)
#pragma unroll
                for (int j = 0; j < 8; ++j)
                    acc[i][j] = fmaf(ar[i], bc[j], acc[i][j]);
        }
        __syncthreads();
    }

    float4 bv0 = *(const float4*)&bias[n0 + tn * 4];
    float4 bv1 = *(const float4*)&bias[n0 + 64 + tn * 4];
    const float bb[8] = {bv0.x, bv0.y, bv0.z, bv0.w, bv1.x, bv1.y, bv1.z, bv1.w};
#pragma unroll
    for (int i = 0; i < 8; ++i) {
        const size_t rowoff = (size_t)(m0 + tm * 8 + i) * 512 + n0;
        float4 o0, o1;
        o0.x = acc[i][0] + bb[0]; o0.y = acc[i][1] + bb[1];
        o0.z = acc[i][2] + bb[2]; o0.w = acc[i][3] + bb[3];
        o1.x = acc[i][4] + bb[4]; o1.y = acc[i][5] + bb[5];
        o1.z = acc[i][6] + bb[6]; o1.w = acc[i][7] + bb[7];
        *(float4*)&C[rowoff + tn * 4] = o0;
        *(float4*)&C[rowoff + 64 + tn * 4] = o1;
    }
}

// ---------------------------------------------------------------------------
// Recurrent scan. Persistent cooperative kernel, grid = 256 WGs.
// Group g (32 groups) handles batch pair (2g, 2g+1) with 8 slice-WGs; slice s
// owns rows [64s, 64s+64) of W_hh resident in LDS (f32, 128 KB, swizzled).
//
// Sync scheme (no fences, no flags, no cache maintenance): h is exchanged as
// packed uint64 {tag=step+1 : 32, f32 h bits : 32} via RELAXED agent-scope
// atomics, which bypass L1/L2 to the coherence point (no buffer_inv/wbl2).
// Readers poll the data itself until all tags match the wanted epoch.
// Parity double-buffer (read slot step&1, write slot (step+1)&1) closes the
// one-step-skew overwrite race: a WG overwrites slot P for step+2 only after
// reading every slice's step+1 from slot P^1, which proves all peers have
// finished reading slot P.
// ---------------------------------------------------------------------------
__global__ __launch_bounds__(256)
void rnn_scan(const float* __restrict__ proj, const float* __restrict__ Whh,
              const float* __restrict__ bhh, float* __restrict__ out,
              float* __restrict__ hidden, unsigned long long* __restrict__ hbuf)
{
    extern __shared__ float lds[];
    float4* Wv   = (float4*)lds;                    // 8192 float4 = 128 KB
    float4* hS   = (float4*)(lds + 32768);          // 2 x 144 float4 (padded)
    float*  part = lds + 32768 + 1152;              // [16][2][64] = 8 KB
    float*  bsl  = lds + 32768 + 1152 + 2048;       // [64]

    const int t    = threadIdx.x;
    const int g    = blockIdx.x & 31;
    const int s    = blockIdx.x >> 5;
    const int b0   = g * 2;
    const int base = s * 64;

    // Load W_hh slice into LDS, float4 layout Wv[k4][r] with XOR swizzle on
    // low 4 row bits so both load and (rq,kq) compute reads are conflict-free.
#pragma unroll 4
    for (int i = 0; i < 32; ++i) {
        const int idx = i * 256 + t;        // 0..8191
        const int r   = idx >> 7;           // 0..63
        const int k4  = idx & 127;          // float4 along k
        float4 v = *(const float4*)&Whh[(size_t)(base + r) * 512 + k4 * 4];
        Wv[k4 * 64 + ((r & 48) | ((r ^ k4) & 15))] = v;
    }
    if (t < 64) bsl[t] = bhh[base + t];

    const int rq = t & 15;   // rows rq, rq+16, rq+32, rq+48
    const int kq = t >> 4;   // k range [kq*32, kq*32+32)

    // reader staging coords: batch elem b (0/1), float4 column c (0..127)
    const int rc = t & 127;
    const int rb = t >> 7;

    __syncthreads();

    for (int step = 0; step < SEQ; ++step) {
        // ---- proj prefetch (independent of h; hidden under poll+compute) --
        float pv = 0.f;
        size_t oidx = 0;
        if (t < 128) {
            const int b = t >> 6;
            const int r = t & 63;
            oidx = (size_t)step * (BATCH * HID) + (size_t)(b0 + b) * HID + base + r;
            pv = proj[oidx];
        }

        // ---- poll + stage h: 4 tagged u64 slots per thread ---------------
        {
            const unsigned long long* src =
                hbuf + (size_t)(step & 1) * (BATCH * HID)
                     + (size_t)(b0 + rb) * HID + rc * 4;
            const unsigned int want = (unsigned int)step;
            float v0 = 0.f, v1 = 0.f, v2 = 0.f, v3 = 0.f;
            bool ok0 = false, ok1 = false, ok2 = false, ok3 = false;
            int spins = 0;
            while (!(ok0 & ok1 & ok2 & ok3)) {
                if (!ok0) {
                    unsigned long long w = __hip_atomic_load(src + 0, __ATOMIC_RELAXED, __HIP_MEMORY_SCOPE_AGENT);
                    if ((unsigned int)(w >> 32) == want) { v0 = __uint_as_float((unsigned int)w); ok0 = true; }
                }
                if (!ok1) {
                    unsigned long long w = __hip_atomic_load(src + 1, __ATOMIC_RELAXED, __HIP_MEMORY_SCOPE_AGENT);
                    if ((unsigned int)(w >> 32) == want) { v1 = __uint_as_float((unsigned int)w); ok1 = true; }
                }
                if (!ok2) {
                    unsigned long long w = __hip_atomic_load(src + 2, __ATOMIC_RELAXED, __HIP_MEMORY_SCOPE_AGENT);
                    if ((unsigned int)(w >> 32) == want) { v2 = __uint_as_float((unsigned int)w); ok2 = true; }
                }
                if (!ok3) {
                    unsigned long long w = __hip_atomic_load(src + 3, __ATOMIC_RELAXED, __HIP_MEMORY_SCOPE_AGENT);
                    if ((unsigned int)(w >> 32) == want) { v3 = __uint_as_float((unsigned int)w); ok3 = true; }
                }
                if (!(ok0 & ok1 & ok2 & ok3)) {
                    __builtin_amdgcn_s_sleep(1);
                    if (++spins > 4096) {           // hang-proofing only
                        __builtin_amdgcn_fence(__ATOMIC_ACQUIRE, "agent");
                        spins = 0;
                    }
                }
            }
            float* dst = (float*)&hS[rb * 144 + rc + (rc >> 3)];
            dst[0] = v0; dst[1] = v1; dst[2] = v2; dst[3] = v3;
        }
        __syncthreads();

        // ---- partial matvec: 4 rows x 32 k per thread, 2 batch elems -----
        float acc0[4] = {0.f, 0.f, 0.f, 0.f};
        float acc1[4] = {0.f, 0.f, 0.f, 0.f};
#pragma unroll
        for (int kb = 0; kb < 8; ++kb) {
            const int k4 = kq * 8 + kb;
            const int hp = k4 + (k4 >> 3);
            float4 ha = hS[hp];
            float4 hb = hS[144 + hp];
#pragma unroll
            for (int rr = 0; rr < 4; ++rr) {
                float4 w = Wv[k4 * 64 + rr * 16 + (rq ^ (k4 & 15))];
                acc0[rr] += w.x * ha.x + w.y * ha.y + w.z * ha.z + w.w * ha.w;
                acc1[rr] += w.x * hb.x + w.y * hb.y + w.z * hb.z + w.w * hb.w;
            }
        }
#pragma unroll
        for (int rr = 0; rr < 4; ++rr) {
            const int r = rq + rr * 16;
            part[kq * 128 + r]      = acc0[rr];
            part[kq * 128 + 64 + r] = acc1[rr];
        }
        __syncthreads();

        // ---- reduce 16 partials, add proj + bias, tanh, publish ----------
        if (t < 128) {
            const int b = t >> 6;
            const int r = t & 63;
            float sum = 0.f;
#pragma unroll
            for (int q = 0; q < 16; ++q) sum += part[q * 128 + b * 64 + r];
            const float y  = pv + bsl[r] + sum;
            const float hn = tanhf(y);
            out[oidx] = hn;
            const unsigned long long pk =
                ((unsigned long long)(unsigned int)(step + 1) << 32) |
                (unsigned long long)__float_as_uint(hn);
            __hip_atomic_store(
                &hbuf[(size_t)((step + 1) & 1) * (BATCH * HID)
                      + (size_t)(b0 + b) * HID + base + r],
                pk, __ATOMIC_RELAXED, __HIP_MEMORY_SCOPE_AGENT);
            if (step == SEQ - 1) hidden[(size_t)(b0 + b) * HID + base + r] = hn;
        }
        __syncthreads();   // protect part/hS reuse next iteration
    }
}

// ---------------------------------------------------------------------------
extern "C" void kernel_launch(void* const* d_in, const int* in_sizes, int n_in,
                              void* d_out, int out_size, void* d_ws, size_t ws_size,
                              hipStream_t stream)
{
    (void)in_sizes; (void)n_in; (void)out_size; (void)ws_size;

    const float* x    = (const float*)d_in[0];
    const float* Wih0 = (const float*)d_in[1];
    const float* Whh0 = (const float*)d_in[2];
    const float* bih0 = (const float*)d_in[3];
    const float* bhh0 = (const float*)d_in[4];
    const float* Wih1 = (const float*)d_in[5];
    const float* Whh1 = (const float*)d_in[6];
    const float* bih1 = (const float*)d_in[7];
    const float* bhh1 = (const float*)d_in[8];

    float* out1   = (float*)d_out;                        // [S][B][H]
    float* hidden = out1 + (size_t)SEQ * BATCH * HID;     // [2][B][H]

    float* proj = (float*)d_ws;                           // [S][B][H] f32
    unsigned long long* hbufA =
        (unsigned long long*)(proj + (size_t)SEQ * BATCH * HID);  // [2][B][H] u64
    unsigned long long* hbufB = hbufA + (size_t)2 * BATCH * HID;  // [2][B][H] u64

    // zero both layers' tagged h-state buffers (tag 0 == epoch 0, h = 0)
    hipMemsetAsync(hbufA, 0, (size_t)4 * BATCH * HID * sizeof(unsigned long long),
                   stream);

    const size_t shmem = (size_t)(32768 + 1152 + 2048 + 64) * sizeof(float); // 144128 B
    (void)hipFuncSetAttribute((const void*)rnn_scan,
                              hipFuncAttributeMaxDynamicSharedMemorySize, (int)shmem);

    // ---- layer 0 ----
    proj_gemm<<<dim3(4096), dim3(256), 0, stream>>>(x, Wih0, bih0, proj);
    {
        const float* p = proj; const float* w = Whh0; const float* bb = bhh0;
        float* o = out1; float* hd = hidden; unsigned long long* hb = hbufA;
        void* args[] = {&p, &w, &bb, &o, &hd, &hb};
        hipLaunchCooperativeKernel((const void*)rnn_scan, dim3(256), dim3(256),
                                   args, (unsigned)shmem, stream);
    }

    // ---- layer 1 (out0 staged in d_out's out1 region) ----
    proj_gemm<<<dim3(4096), dim3(256), 0, stream>>>(out1, Wih1, bih1, proj);
    {
        const float* p = proj; const float* w = Whh1; const float* bb = bhh1;
        float* o = out1; float* hd = hidden + BATCH * HID; unsigned long long* hb = hbufB;
        void* args[] = {&p, &w, &bb, &o, &hd, &hb};
        hipLaunchCooperativeKernel((const void*)rnn_scan, dim3(256), dim3(256),
                                   args, (unsigned)shmem, stream);
    }
}